// Round 1
// baseline (57.873 us; speedup 1.0000x reference)
//
#include <hip/hip_runtime.h>
#include <hip/hip_bf16.h>

// SPU transformer bound-propagation: pure elementwise over N rows.
// Each thread handles one row: float2 loads from 4 inputs, float2 store.

__device__ __forceinline__ float spu_f(float x) {
    // x >= 0: x*x - 0.5 ; else sigmoid(-x) - 1 = 1/(1+exp(x)) - 1
    if (x >= 0.0f) {
        return x * x - 0.5f;
    } else {
        return 1.0f / (1.0f + __expf(x)) - 1.0f;
    }
}

__global__ void spu_kernel(const float2* __restrict__ bounds,
                           const float2* __restrict__ last_slopes,
                           const float2* __restrict__ last_shifts,
                           const float2* __restrict__ last_bounds,
                           float2* __restrict__ out,
                           int n) {
    int i = blockIdx.x * blockDim.x + threadIdx.x;
    if (i >= n) return;

    float2 b  = bounds[i];
    float2 ls = last_slopes[i];
    float2 lh = last_shifts[i];
    float2 lb2 = last_bounds[i];

    float l = b.x, u = b.y;
    float vl = spu_f(l);
    float vu = spu_f(u);
    float diff = u - l;

    bool neg   = (u <= 0.0f);
    bool pos   = (l >= 0.0f);
    bool cross = !(neg || pos);

    float all_slopes = (vu - vl) / diff;
    float slope_u = (pos || cross) ? all_slopes : 0.0f;
    float slope_l = neg ? all_slopes : 0.0f;

    bool sw = (all_slopes < 0.0f);
    float v_l = sw ? vu : vl;
    float v_u = sw ? vl : vu;
    float b_l = sw ? u  : l;
    float b_u = sw ? l  : u;

    float bnd_l = cross ? -0.5f : v_l;
    float bnd_u = v_u;

    float shift_u = v_u - slope_u * b_u;
    float shift_l = cross ? -0.5f : (v_l - slope_l * b_l);

    float Ud = slope_u * ls.y;
    float UV = slope_u * lh.y + shift_u;
    float Ld = slope_l * ls.x;
    float LV = slope_l * lh.x + shift_l;

    float lb = fmaxf(Ld, 0.0f) * lb2.x + fminf(Ld, 0.0f) * lb2.y + LV;
    float ub = fmaxf(Ud, 0.0f) * lb2.y + fminf(Ud, 0.0f) * lb2.x + UV;

    float out_l = (lb > bnd_l) ? lb : bnd_l;
    float out_u = (ub < bnd_u) ? ub : bnd_u;

    out[i] = make_float2(out_l, out_u);
}

extern "C" void kernel_launch(void* const* d_in, const int* in_sizes, int n_in,
                              void* d_out, int out_size, void* d_ws, size_t ws_size,
                              hipStream_t stream) {
    const float2* bounds      = (const float2*)d_in[0];
    const float2* last_slopes = (const float2*)d_in[1];
    const float2* last_shifts = (const float2*)d_in[2];
    const float2* last_bounds = (const float2*)d_in[3];
    float2* out = (float2*)d_out;

    int n = in_sizes[0] / 2;  // bounds is (N, 2)
    int block = 256;
    int grid = (n + block - 1) / block;
    spu_kernel<<<grid, block, 0, stream>>>(bounds, last_slopes, last_shifts,
                                           last_bounds, out, n);
}